// Round 9
// baseline (325.555 us; speedup 1.0000x reference)
//
#include <hip/hip_runtime.h>
#include <hip/hip_bf16.h>

#define NENT 40000
#define NREL 20
#define DIM 128
#define NBASIS 8
#define KTOT 1152              // 8*128 (G) + 128 (x)
#define P0END 20480            // pass split (320 tiles of 64)
#define SCANBLK 157            // ceil(40000/256)

typedef __attribute__((ext_vector_type(8))) short sh8;
typedef __attribute__((ext_vector_type(4))) float fx4;

__device__ __forceinline__ short f2bf(float f) {
    union { __hip_bfloat16 h; short s; } u;
    u.h = __float2bfloat16(f);
    return u.s;
}

// f32 -> bf16 copy (x panel for layer 1 + gather source)
__global__ void k_tobf(const float* __restrict__ x, ushort* __restrict__ xb, int nelem) {
    int i = (blockIdx.x * 256 + threadIdx.x) * 4;
    if (i >= nelem) return;
    float4 v = *(const float4*)(x + i);
    ushort4 o;
    o.x = (ushort)f2bf(v.x); o.y = (ushort)f2bf(v.y);
    o.z = (ushort)f2bf(v.z); o.w = (ushort)f2bf(v.w);
    *(ushort4*)(xb + i) = o;
}

// Fragment-order stacked B: ks 0..7 = basis[ks] (k-rows i), ks 8 = root.
// B-frag: lane holds B[k = kk*32 + lhi*8 + e][col = c*16 + l15].
__global__ void k_wfrag9(const float* __restrict__ basis, const float* __restrict__ root,
                         short* __restrict__ Wfb) {
    int t = blockIdx.x * 256 + threadIdx.x;
    if (t >= 9 * 16384) return;
    int ks = t / 16384;
    int rem = t & 16383;
    int i = rem >> 7, o = rem & 127;
    float v = (ks < 8) ? basis[ks * 16384 + i * 128 + o] : root[i * 128 + o];
    int c = o >> 4, l15 = o & 15;
    int kk = i >> 5, lhi = (i >> 3) & 3, e = i & 7;
    int lane = l15 + lhi * 16;
    Wfb[(size_t)ks * 16384 + (size_t)(((c * 4 + kk) * 64 + lane) << 3) + e] = f2bf(v);
}

__global__ void k_hist(const int* __restrict__ dst, int E, int* __restrict__ hist) {
    int e = blockIdx.x * 256 + threadIdx.x;
    if (e < E) atomicAdd(&hist[dst[e]], 1);
}

// -------- 3-phase parallel scan over NENT bins --------
__global__ void k_scan1(const int* __restrict__ hist, int* __restrict__ offs,
                        int* __restrict__ bsum) {
    __shared__ int ps[256];
    int t = threadIdx.x;
    int i = blockIdx.x * 256 + t;
    int v = (i < NENT) ? hist[i] : 0;
    ps[t] = v;
    __syncthreads();
    for (int off = 1; off < 256; off <<= 1) {
        int u = (t >= off) ? ps[t - off] : 0;
        __syncthreads();
        ps[t] += u;
        __syncthreads();
    }
    if (i < NENT) offs[i] = ps[t] - v;
    if (t == 255) bsum[blockIdx.x] = ps[255];
}

__global__ void k_scan2(int* __restrict__ bsum) {
    __shared__ int ps[256];
    int t = threadIdx.x;
    int v = (t < SCANBLK) ? bsum[t] : 0;
    ps[t] = v;
    __syncthreads();
    for (int off = 1; off < 256; off <<= 1) {
        int u = (t >= off) ? ps[t - off] : 0;
        __syncthreads();
        ps[t] += u;
        __syncthreads();
    }
    if (t < SCANBLK) bsum[t] = ps[t] - v;
}

__global__ void k_scan3(int* __restrict__ offs, int* __restrict__ cursor,
                        const int* __restrict__ bsum, int E) {
    int i = blockIdx.x * 256 + threadIdx.x;
    if (i < NENT) {
        int o = offs[i] + bsum[blockIdx.x];
        offs[i] = o;
        cursor[i] = o;
    }
    if (i == 0) offs[NENT] = E;
}

// counting-sort by dst: packed = src | et<<16
__global__ void k_scatter(const int* __restrict__ et, const int* __restrict__ srcA,
                          const int* __restrict__ dstA, int E,
                          int* __restrict__ cursor, unsigned* __restrict__ packed) {
    int e = blockIdx.x * 256 + threadIdx.x;
    if (e >= E) return;
    int pos = atomicAdd(&cursor[dstA[e]], 1);
    packed[pos] = (unsigned)srcA[e] | ((unsigned)et[e] << 16);
}

// One wave per dst node: G[n][b][:] = (1/deg) * sum_e comp[et,b]*x[src].
__global__ __launch_bounds__(256) void k_gather(
    const ushort* __restrict__ xb, const unsigned* __restrict__ packed,
    const int* __restrict__ offs, const float* __restrict__ comp,
    ushort* __restrict__ G, int n0, int n1) {
    __shared__ __align__(16) float cl[NREL * NBASIS];
    int t = threadIdx.x;
    if (t < NREL * NBASIS) cl[t] = comp[t];
    __syncthreads();
    int n = n0 + blockIdx.x * 4 + (t >> 6);
    if (n >= n1) return;
    int lane = t & 63;
    int beg = offs[n];
    int cnt = offs[n + 1] - beg;

    float a0[NBASIS], a1[NBASIS];
#pragma unroll
    for (int b = 0; b < NBASIS; ++b) { a0[b] = 0.f; a1[b] = 0.f; }

    const unsigned* xrow = (const unsigned*)xb + lane;
    unsigned pA = 0, pB = 0, rA = 0;
    if (cnt > 0) { pA = packed[beg]; rA = xrow[(size_t)(pA & 0xFFFFu) * 64]; }
    if (cnt > 1) pB = packed[beg + 1];

    for (int i = 0; i < cnt; ++i) {
        unsigned pC = (i + 2 < cnt) ? packed[beg + i + 2] : 0u;
        unsigned rB = xrow[(size_t)(pB & 0xFFFFu) * 64];
        float xlo = __uint_as_float(rA << 16);
        float xhi = __uint_as_float(rA & 0xFFFF0000u);
        int et = pA >> 16;
        float4 cwa = *(const float4*)&cl[et * NBASIS];
        float4 cwb = *(const float4*)&cl[et * NBASIS + 4];
        a0[0] += cwa.x * xlo; a1[0] += cwa.x * xhi;
        a0[1] += cwa.y * xlo; a1[1] += cwa.y * xhi;
        a0[2] += cwa.z * xlo; a1[2] += cwa.z * xhi;
        a0[3] += cwa.w * xlo; a1[3] += cwa.w * xhi;
        a0[4] += cwb.x * xlo; a1[4] += cwb.x * xhi;
        a0[5] += cwb.y * xlo; a1[5] += cwb.y * xhi;
        a0[6] += cwb.z * xlo; a1[6] += cwb.z * xhi;
        a0[7] += cwb.w * xlo; a1[7] += cwb.w * xhi;
        pA = pB; pB = pC; rA = rB;
    }

    float inv = 1.f / (float)(cnt < 1 ? 1 : cnt);
    unsigned* go = (unsigned*)(G + (size_t)(n - n0) * 1024) + lane;
#pragma unroll
    for (int b = 0; b < NBASIS; ++b) {
        unsigned lo = (unsigned)(ushort)f2bf(a0[b] * inv);
        unsigned hi = (unsigned)(ushort)f2bf(a1[b] * inv);
        go[b * 64] = lo | (hi << 16);
    }
}

// Dense MFMA GEMM, register-pipelined: C[64 x 128] = [G | xpan] @ Wfb + bias.
// 2x2 wave grid: wave = 32 rows x 64 cols. A+B double-buffered in registers.
// launch_bounds(256,1): grid is ~1 block/CU, so grant the full VGPR budget —
// the depth-2 pipeline needs ~192 VGPRs of in-flight load destinations.
__global__ __launch_bounds__(256, 1) void k_bgemm(
    const ushort* __restrict__ G, const ushort* __restrict__ xpan,
    const short* __restrict__ Wfb, const float* __restrict__ bias,
    ushort* __restrict__ outbf, float* __restrict__ outf, int n0, int act) {
    int t = threadIdx.x;
    int lane = t & 63, wid = t >> 6;
    int wr = wid >> 1, wc = wid & 1;          // 2x2 wave grid
    int l15 = lane & 15, lhi = lane >> 4;
    int wc4 = wc * 4;

    int row0 = n0 + blockIdx.x * 64 + wr * 32;       // wave's first row
    const ushort* Ar0 = G + (size_t)(row0 - n0 + l15) * 1024 + lhi * 8;
    const ushort* Ar1 = Ar0 + (size_t)16 * 1024;
    const ushort* Xr0 = xpan + (size_t)(row0 + l15) * 128 + lhi * 8;
    const ushort* Xr1 = Xr0 + (size_t)16 * 128;

    fx4 acc[2][4];
#pragma unroll
    for (int rg = 0; rg < 2; ++rg)
#pragma unroll
        for (int c = 0; c < 4; ++c) acc[rg][c] = (fx4){0.f, 0.f, 0.f, 0.f};

    auto loadA = [&](sh8 (&a)[2][4], int ks) {
        if (ks < 8) {
#pragma unroll
            for (int kk = 0; kk < 4; ++kk) {
                a[0][kk] = *(const sh8*)(Ar0 + ks * 128 + kk * 32);
                a[1][kk] = *(const sh8*)(Ar1 + ks * 128 + kk * 32);
            }
        } else {
#pragma unroll
            for (int kk = 0; kk < 4; ++kk) {
                a[0][kk] = *(const sh8*)(Xr0 + kk * 32);
                a[1][kk] = *(const sh8*)(Xr1 + kk * 32);
            }
        }
    };
    auto loadB = [&](sh8 (&b)[4][4], int ks) {
        const sh8* W8 = (const sh8*)(Wfb + (size_t)ks * 16384);
#pragma unroll
        for (int c = 0; c < 4; ++c)
#pragma unroll
            for (int kk = 0; kk < 4; ++kk)
                b[c][kk] = W8[((wc4 + c) * 4 + kk) * 64 + lane];
    };
    auto step = [&](const sh8 (&a)[2][4], const sh8 (&b)[4][4]) {
#pragma unroll
        for (int rg = 0; rg < 2; ++rg)
#pragma unroll
            for (int c = 0; c < 4; ++c)
#pragma unroll
                for (int kk = 0; kk < 4; ++kk)
                    acc[rg][c] = __builtin_amdgcn_mfma_f32_16x16x32_bf16(
                        a[rg][kk], b[c][kk], acc[rg][c], 0, 0, 0);
    };

    sh8 aA[2][4], aB[2][4], bA[4][4], bB[4][4];
    loadA(aA, 0); loadB(bA, 0);
    loadA(aB, 1); loadB(bB, 1); step(aA, bA);
    loadA(aA, 2); loadB(bA, 2); step(aB, bB);
    loadA(aB, 3); loadB(bB, 3); step(aA, bA);
    loadA(aA, 4); loadB(bA, 4); step(aB, bB);
    loadA(aB, 5); loadB(bB, 5); step(aA, bA);
    loadA(aA, 6); loadB(bA, 6); step(aB, bB);
    loadA(aB, 7); loadB(bB, 7); step(aA, bA);
    loadA(aA, 8); loadB(bA, 8); step(aB, bB);
    step(aA, bA);

    int orow0 = row0 + lhi * 4;   // + rg*16 + j
#pragma unroll
    for (int rg = 0; rg < 2; ++rg) {
#pragma unroll
        for (int c = 0; c < 4; ++c) {
            int col = wc * 64 + c * 16 + l15;
            float bv = bias[col];
#pragma unroll
            for (int j = 0; j < 4; ++j) {
                float v = acc[rg][c][j] + bv;
                if (act) {
                    v = tanhf(v);
                    outbf[(size_t)(orow0 + rg * 16 + j) * 128 + col] = (ushort)f2bf(v);
                } else {
                    outf[(size_t)(orow0 + rg * 16 + j) * 128 + col] = v;
                }
            }
        }
    }
}

__global__ void k_rel(const float* __restrict__ rel, const float* __restrict__ wrel,
                      float* __restrict__ out, int nrows) {
    int idx = blockIdx.x * 256 + threadIdx.x;
    if (idx >= nrows * DIM) return;
    int j = idx >> 7, o = idx & 127;
    float s = 0.f;
    for (int i = 0; i < DIM; ++i) s += rel[j * DIM + i] * wrel[i * DIM + o];
    out[idx] = s;
}

extern "C" void kernel_launch(void* const* d_in, const int* in_sizes, int n_in,
                              void* d_out, int out_size, void* d_ws, size_t ws_size,
                              hipStream_t stream) {
    const int* edge_index = (const int*)d_in[0];
    const int* edge_type  = (const int*)d_in[1];
    const float* init_embed = (const float*)d_in[2];
    const float* init_rel   = (const float*)d_in[3];
    const float* w_rel      = (const float*)d_in[4];
    const float* comp1  = (const float*)d_in[5];
    const float* basis1 = (const float*)d_in[6];
    const float* root1  = (const float*)d_in[7];
    const float* bias1  = (const float*)d_in[8];
    const float* comp2  = (const float*)d_in[9];
    const float* basis2 = (const float*)d_in[10];
    const float* root2  = (const float*)d_in[11];
    const float* bias2  = (const float*)d_in[12];

    int E = in_sizes[1];
    const int* src = edge_index;
    const int* dst = edge_index + E;
    int relrows = in_sizes[3] / DIM;   // 40

    // workspace layout (16B-aligned regions)
    short* Wfb1 = (short*)d_ws;                          // 9*16384 shorts
    short* Wfb2 = Wfb1 + (size_t)9 * 16384;
    ushort* xb  = (ushort*)(Wfb2 + (size_t)9 * 16384);   // 40000*128 bf16
    ushort* hb  = xb + (size_t)NENT * DIM;               // 40000*128 bf16
    ushort* G   = hb + (size_t)NENT * DIM;               // 20480*1024 bf16 (42 MB)
    int* hist   = (int*)(G + (size_t)P0END * 1024);      // 40000 (pad 40004)
    int* offs   = hist + 40004;
    int* cursor = offs + 40004;
    int* bsum   = cursor + 40004;                        // 157 (pad 160)
    unsigned* packed = (unsigned*)(bsum + 160);          // E

    float* outx = (float*)d_out;
    float* outr = outx + (size_t)NENT * DIM;

    hipMemsetAsync(hist, 0, NENT * sizeof(int), stream);

    k_tobf<<<(NENT * DIM / 4 + 255) / 256, 256, 0, stream>>>(init_embed, xb, NENT * DIM);
    k_wfrag9<<<(9 * 16384 + 255) / 256, 256, 0, stream>>>(basis1, root1, Wfb1);
    k_wfrag9<<<(9 * 16384 + 255) / 256, 256, 0, stream>>>(basis2, root2, Wfb2);
    k_hist<<<(E + 255) / 256, 256, 0, stream>>>(dst, E, hist);
    k_scan1<<<SCANBLK, 256, 0, stream>>>(hist, offs, bsum);
    k_scan2<<<1, 256, 0, stream>>>(bsum);
    k_scan3<<<SCANBLK, 256, 0, stream>>>(offs, cursor, bsum, E);
    k_scatter<<<(E + 255) / 256, 256, 0, stream>>>(edge_type, src, dst, E, cursor, packed);

    // layer 1: hb = bf16(tanh(G@W~1 + x@root1 + bias1)), two node passes
    k_gather<<<P0END / 4, 256, 0, stream>>>(xb, packed, offs, comp1, G, 0, P0END);
    k_bgemm<<<P0END / 64, 256, 0, stream>>>(G, xb, Wfb1, bias1, hb, outx, 0, 1);
    k_gather<<<(NENT - P0END) / 4, 256, 0, stream>>>(xb, packed, offs, comp1, G, P0END, NENT);
    k_bgemm<<<(NENT - P0END) / 64, 256, 0, stream>>>(G, xb, Wfb1, bias1, hb, outx, P0END, 1);

    // layer 2: out = G@W~2 + h@root2 + bias2 (f32 to d_out)
    k_gather<<<P0END / 4, 256, 0, stream>>>(hb, packed, offs, comp2, G, 0, P0END);
    k_bgemm<<<P0END / 64, 256, 0, stream>>>(G, hb, Wfb2, bias2, hb, outx, 0, 0);
    k_gather<<<(NENT - P0END) / 4, 256, 0, stream>>>(hb, packed, offs, comp2, G, P0END, NENT);
    k_bgemm<<<(NENT - P0END) / 64, 256, 0, stream>>>(G, hb, Wfb2, bias2, hb, outx, P0END, 0);

    // relation output: r = init_rel @ w_rel
    k_rel<<<(relrows * DIM + 255) / 256, 256, 0, stream>>>(init_rel, w_rel, outr, relrows);
}